// Round 9
// baseline (360.213 us; speedup 1.0000x reference)
//
#include <hip/hip_runtime.h>

// Problem constants (from reference setup_inputs): B=32, N=2048, D=256, E=2^20
#define NB   32
#define NN   2048
#define RTOT (NB * NN)   // 65536 flattened rows
#define DIM  256
#define DIM2 512         // output row stride (concat of accumulator and x)
#define CAP  128         // R8-fallback bucket capacity
#define CAPX 32          // per-XCD-copy segment capacity (Poisson(4); 64B line)

#define EPT    4
#define NPASS  8
#define PSHIFT 13        // log2(RTOT / NPASS)
#define CONV_BLOCKS   512
#define CONV_PER_BLK  (RTOT * DIM / 4 / CONV_BLOCKS)   // 8192 vf4 per block

// gather XCD swizzle (R2, proven): neighbors never cross batches; a batch
// slice fits one XCD's L2. Batch b's blocks all land on XCD b%8.
#define BLKS_PER_BATCH (NN / 4)
#define GATHER_BLOCKS  (RTOT / 4)      // 16384

// R9: fill was bound by cross-XCD writeback/migration (WRITE 99MB for 4MB
// payload; all 8 XCDs dirty every bucket/cnt line through non-coherent L2s).
// Fix = partition EDGES (not rows -- R4's row-partition amplified reads 8x
// and regressed): block p inserts its slice into bucket copy (p&7). Each
// (row,copy) segment is a private 64B-aligned line; each cnt copy a private
// 256KB range. Correct under ANY block->XCD mapping; fast under round-robin.

typedef float vf4 __attribute__((ext_vector_type(4)));
typedef unsigned short vu4 __attribute__((ext_vector_type(4)));

// Zero per-row counters: 8 private copies (512K ints) for priv path.
__global__ __launch_bounds__(256) void zero_counts(int* __restrict__ c, int n) {
    int i = blockIdx.x * 256 + threadIdx.x;
    if (i < n) c[i] = 0;
}

// Unpack 4 bf16 (two dwords) into f32x4 via exponent-preserving shifts.
__device__ inline vf4 bf16x4_to_f32(unsigned lo, unsigned hi) {
    vf4 v;
    v[0] = __uint_as_float(lo << 16);
    v[1] = __uint_as_float(lo & 0xffff0000u);
    v[2] = __uint_as_float(hi << 16);
    v[3] = __uint_as_float(hi & 0xffff0000u);
    return v;
}

__device__ inline void conv_path(const float* __restrict__ x,
                                 unsigned short* __restrict__ xb, int cb) {
    const vf4* x4 = (const vf4*)x;
    vu4* o4 = (vu4*)xb;
    int beg = cb * CONV_PER_BLK;
    for (int i = beg + (int)threadIdx.x; i < beg + CONV_PER_BLK; i += 256) {
        vf4 v = x4[i];
        vu4 o;
#pragma unroll
        for (int k = 0; k < 4; ++k) {
            unsigned u = __float_as_uint(v[k]);
            unsigned r = u + 0x7fffu + ((u >> 16) & 1u);   // RNE
            o[k] = (unsigned short)(r >> 16);
        }
        o4[i] = o;
    }
}

// ---------------- R9 private-bucket fill (+fused convert) ----------------
// bucket layout: row stride 256 entries (512B); copy k at +k*32 (one 64B line).
__global__ __launch_bounds__(256) void fill_conv_priv(const int* __restrict__ b,
                                                      const int* __restrict__ s,
                                                      const int* __restrict__ d,
                                                      int* __restrict__ cnt8,
                                                      unsigned short* __restrict__ bucket,
                                                      const float* __restrict__ x,
                                                      unsigned short* __restrict__ xb,
                                                      int E, int fillBlocks) {
    if ((int)blockIdx.x >= fillBlocks) {
        conv_path(x, xb, blockIdx.x - fillBlocks);
        return;
    }
    int kcopy = blockIdx.x & 7;                  // private copy (XCD under RR)
    int* cnt = cnt8 + kcopy * RTOT;
    int koff = kcopy * CAPX;

    int t = blockIdx.x * 256 + threadIdx.x;
    int base = t * EPT;
    int rs[EPT], rd[EPT];

    if (base + EPT <= E) {
        int4 b4 = ((const int4*)b)[t];
        int4 s4 = ((const int4*)s)[t];
        int4 d4 = ((const int4*)d)[t];
        rs[0] = b4.x * NN + s4.x;  rd[0] = b4.x * NN + d4.x;
        rs[1] = b4.y * NN + s4.y;  rd[1] = b4.y * NN + d4.y;
        rs[2] = b4.z * NN + s4.z;  rd[2] = b4.z * NN + d4.z;
        rs[3] = b4.w * NN + s4.w;  rd[3] = b4.w * NN + d4.w;
    } else {
#pragma unroll
        for (int i = 0; i < EPT; ++i) {
            int e = base + i;
            if (e < E) {
                int bb = b[e];
                rs[i] = bb * NN + s[e];
                rd[i] = bb * NN + d[e];
            } else { rs[i] = -1; rd[i] = -1; }
        }
    }

    for (int p = 0; p < NPASS; ++p) {
#pragma unroll
        for (int i = 0; i < EPT; ++i) {
            if ((rs[i] >> PSHIFT) == p) {
                int q = atomicAdd(&cnt[rs[i]], 1);
                if (q < CAPX) bucket[(long)rs[i] * 256 + koff + q] = (unsigned short)rd[i];
            }
            if ((rd[i] >> PSHIFT) == p) {
                int q = atomicAdd(&cnt[rd[i]], 1);
                if (q < CAPX) bucket[(long)rd[i] * 256 + koff + q] = (unsigned short)rs[i];
            }
        }
    }
}

// ---------------- R9 gather over 8 private segments ----------------
// Pair machinery from R8 (lanes 0-31 even neighbor, 32-63 odd; one uint4 =
// 8 bf16 per lane; shfl_xor(32) combine per row). Inner loop phase-split:
// phase 1 issues all active segment loads (8 named regs, scalar-uniform
// branches, no waits) -> ~8 loads in flight; phase 2 accumulates.
__global__ __launch_bounds__(256) void gather_priv(const float* __restrict__ x,
                                                   const unsigned short* __restrict__ xb,
                                                   const int* __restrict__ cnt8,
                                                   const unsigned short* __restrict__ bucket,
                                                   float* __restrict__ out) {
    int p = blockIdx.x;
    int l;
    if (gridDim.x == GATHER_BLOCKS) {
        int xcd = p & 7;
        int u   = p >> 3;
        int bat = xcd + 8 * (u >> 9);
        l = bat * BLKS_PER_BATCH + (u & (BLKS_PER_BATCH - 1));
    } else {
        l = p;
    }

    int lane = threadIdx.x & 63;
    int half = lane >> 5;
    int sub  = lane & 31;
    int row = __builtin_amdgcn_readfirstlane((l << 2) + (threadIdx.x >> 6));
    if (row >= RTOT) return;

    // 8 private counts (uniform -> SGPRs).
    int n0 = __builtin_amdgcn_readfirstlane(cnt8[0 * RTOT + row]); if (n0 > CAPX) n0 = CAPX;
    int n1 = __builtin_amdgcn_readfirstlane(cnt8[1 * RTOT + row]); if (n1 > CAPX) n1 = CAPX;
    int n2 = __builtin_amdgcn_readfirstlane(cnt8[2 * RTOT + row]); if (n2 > CAPX) n2 = CAPX;
    int n3 = __builtin_amdgcn_readfirstlane(cnt8[3 * RTOT + row]); if (n3 > CAPX) n3 = CAPX;
    int n4 = __builtin_amdgcn_readfirstlane(cnt8[4 * RTOT + row]); if (n4 > CAPX) n4 = CAPX;
    int n5 = __builtin_amdgcn_readfirstlane(cnt8[5 * RTOT + row]); if (n5 > CAPX) n5 = CAPX;
    int n6 = __builtin_amdgcn_readfirstlane(cnt8[6 * RTOT + row]); if (n6 > CAPX) n6 = CAPX;
    int n7 = __builtin_amdgcn_readfirstlane(cnt8[7 * RTOT + row]); if (n7 > CAPX) n7 = CAPX;

    const unsigned* l32 = (const unsigned*)(bucket + (size_t)row * 256);
    const uint4* xb4 = (const uint4*)xb;
    const vf4*   x4  = (const vf4*)x;
    vf4 xown = x4[((size_t)row << 6) + lane];

    vf4 aA0 = (vf4){0.f,0.f,0.f,0.f};
    vf4 aB0 = (vf4){0.f,0.f,0.f,0.f};
    vf4 aA1 = (vf4){0.f,0.f,0.f,0.f};
    vf4 aB1 = (vf4){0.f,0.f,0.f,0.f};

    int p0 = n0 >> 1, p1 = n1 >> 1, p2 = n2 >> 1, p3 = n3 >> 1;
    int p4 = n4 >> 1, p5 = n5 >> 1, p6 = n6 >> 1, p7 = n7 >> 1;
    int maxp = p0;
    if (p1 > maxp) maxp = p1;  if (p2 > maxp) maxp = p2;
    if (p3 > maxp) maxp = p3;  if (p4 > maxp) maxp = p4;
    if (p5 > maxp) maxp = p5;  if (p6 > maxp) maxp = p6;
    if (p7 > maxp) maxp = p7;

#define SEG_LOAD(K, PK, Q)                                             \
    uint4 Q;                                                           \
    if (i < (PK)) {                                                    \
        unsigned w_ = l32[(K) * 16 + i];                               \
        unsigned r_ = half ? (w_ >> 16) : (w_ & 0xffffu);              \
        Q = xb4[(size_t)((r_ << 5) + sub)];                            \
    }
#define SEG_ACC(PK, Q, AA, BB)                                         \
    if (i < (PK)) {                                                    \
        (AA) += bf16x4_to_f32((Q).x, (Q).y);                           \
        (BB) += bf16x4_to_f32((Q).z, (Q).w);                           \
    }

    for (int i = 0; i < maxp; ++i) {
        SEG_LOAD(0, p0, q0) SEG_LOAD(1, p1, q1)
        SEG_LOAD(2, p2, q2) SEG_LOAD(3, p3, q3)
        SEG_LOAD(4, p4, q4) SEG_LOAD(5, p5, q5)
        SEG_LOAD(6, p6, q6) SEG_LOAD(7, p7, q7)
        SEG_ACC(p0, q0, aA0, aB0) SEG_ACC(p1, q1, aA1, aB1)
        SEG_ACC(p2, q2, aA0, aB0) SEG_ACC(p3, q3, aA1, aB1)
        SEG_ACC(p4, q4, aA0, aB0) SEG_ACC(p5, q5, aA1, aB1)
        SEG_ACC(p6, q6, aA0, aB0) SEG_ACC(p7, q7, aA1, aB1)
    }
#undef SEG_LOAD
#undef SEG_ACC

    // Odd tails: last entry of each odd-count segment (low half-word).
    // Half-wave utilization, but <=8 independent loads issue together.
#define SEG_ODD(K, NK, PK)                                             \
    if ((NK) & 1) {                                                    \
        unsigned w_ = l32[(K) * 16 + (PK)];                            \
        if (half == 0) {                                               \
            unsigned r_ = w_ & 0xffffu;                                \
            uint4 q_ = xb4[(size_t)((r_ << 5) + sub)];                 \
            aA0 += bf16x4_to_f32(q_.x, q_.y);                          \
            aB0 += bf16x4_to_f32(q_.z, q_.w);                          \
        }                                                              \
    }
    SEG_ODD(0, n0, p0) SEG_ODD(1, n1, p1) SEG_ODD(2, n2, p2)
    SEG_ODD(3, n3, p3) SEG_ODD(4, n4, p4) SEG_ODD(5, n5, p5)
    SEG_ODD(6, n6, p6) SEG_ODD(7, n7, p7)
#undef SEG_ODD

    vf4 aA = aA0 + aA1;
    vf4 aB = aB0 + aB1;
#pragma unroll
    for (int k = 0; k < 4; ++k) {
        aA[k] += __shfl_xor(aA[k], 32, 64);
        aB[k] += __shfl_xor(aB[k], 32, 64);
    }

    vf4* o = (vf4*)(out + (size_t)row * DIM2);
    if (half == 0) {
        __builtin_nontemporal_store(aA, &o[2 * sub]);
        __builtin_nontemporal_store(aB, &o[2 * sub + 1]);
    }
    __builtin_nontemporal_store(xown, &o[64 + lane]);
}

// ---------------- R8 fallback path (proven 297us) ----------------
__global__ __launch_bounds__(256) void fill_conv(const int* __restrict__ b,
                                                 const int* __restrict__ s,
                                                 const int* __restrict__ d,
                                                 int* __restrict__ cnt,
                                                 unsigned short* __restrict__ bucket,
                                                 const float* __restrict__ x,
                                                 unsigned short* __restrict__ xb,
                                                 int E, int fillBlocks) {
    if ((int)blockIdx.x >= fillBlocks) {
        conv_path(x, xb, blockIdx.x - fillBlocks);
        return;
    }
    int t = blockIdx.x * 256 + threadIdx.x;
    int base = t * EPT;
    int rs[EPT], rd[EPT];
    if (base + EPT <= E) {
        int4 b4 = ((const int4*)b)[t];
        int4 s4 = ((const int4*)s)[t];
        int4 d4 = ((const int4*)d)[t];
        rs[0] = b4.x * NN + s4.x;  rd[0] = b4.x * NN + d4.x;
        rs[1] = b4.y * NN + s4.y;  rd[1] = b4.y * NN + d4.y;
        rs[2] = b4.z * NN + s4.z;  rd[2] = b4.z * NN + d4.z;
        rs[3] = b4.w * NN + s4.w;  rd[3] = b4.w * NN + d4.w;
    } else {
#pragma unroll
        for (int i = 0; i < EPT; ++i) {
            int e = base + i;
            if (e < E) {
                int bb = b[e];
                rs[i] = bb * NN + s[e];
                rd[i] = bb * NN + d[e];
            } else { rs[i] = -1; rd[i] = -1; }
        }
    }
    for (int p = 0; p < NPASS; ++p) {
#pragma unroll
        for (int i = 0; i < EPT; ++i) {
            if ((rs[i] >> PSHIFT) == p) {
                int q = atomicAdd(&cnt[rs[i]], 1);
                if (q < CAP) bucket[(long)rs[i] * CAP + q] = (unsigned short)rd[i];
            }
            if ((rd[i] >> PSHIFT) == p) {
                int q = atomicAdd(&cnt[rd[i]], 1);
                if (q < CAP) bucket[(long)rd[i] * CAP + q] = (unsigned short)rs[i];
            }
        }
    }
}

__global__ __launch_bounds__(256) void gather_bf16(const float* __restrict__ x,
                                                   const unsigned short* __restrict__ xb,
                                                   const int* __restrict__ cnt,
                                                   const unsigned short* __restrict__ bucket,
                                                   float* __restrict__ out) {
    int p = blockIdx.x;
    int l;
    if (gridDim.x == GATHER_BLOCKS) {
        int xcd = p & 7;
        int u   = p >> 3;
        int bat = xcd + 8 * (u >> 9);
        l = bat * BLKS_PER_BATCH + (u & (BLKS_PER_BATCH - 1));
    } else {
        l = p;
    }
    int lane = threadIdx.x & 63;
    int half = lane >> 5;
    int sub  = lane & 31;
    int row = __builtin_amdgcn_readfirstlane((l << 2) + (threadIdx.x >> 6));
    if (row >= RTOT) return;
    int n = __builtin_amdgcn_readfirstlane(cnt[row]);
    if (n > CAP) n = CAP;
    const unsigned* l32 = (const unsigned*)(bucket + (size_t)row * CAP);
    const uint4* xb4 = (const uint4*)xb;
    const vf4*   x4  = (const vf4*)x;
    vf4 xown = x4[((size_t)row << 6) + lane];
    vf4 aA0 = (vf4){0.f,0.f,0.f,0.f};
    vf4 aB0 = (vf4){0.f,0.f,0.f,0.f};
    vf4 aA1 = (vf4){0.f,0.f,0.f,0.f};
    vf4 aB1 = (vf4){0.f,0.f,0.f,0.f};
    int pairs = n >> 1;
    int j = 0;
    for (; j + 4 <= pairs; j += 4) {
        unsigned w0 = l32[j + 0], w1 = l32[j + 1], w2 = l32[j + 2], w3 = l32[j + 3];
        unsigned r0 = half ? (w0 >> 16) : (w0 & 0xffffu);
        unsigned r1 = half ? (w1 >> 16) : (w1 & 0xffffu);
        unsigned r2 = half ? (w2 >> 16) : (w2 & 0xffffu);
        unsigned r3 = half ? (w3 >> 16) : (w3 & 0xffffu);
        uint4 q0 = xb4[(size_t)((r0 << 5) + sub)];
        uint4 q1 = xb4[(size_t)((r1 << 5) + sub)];
        uint4 q2 = xb4[(size_t)((r2 << 5) + sub)];
        uint4 q3 = xb4[(size_t)((r3 << 5) + sub)];
        aA0 += bf16x4_to_f32(q0.x, q0.y); aB0 += bf16x4_to_f32(q0.z, q0.w);
        aA1 += bf16x4_to_f32(q1.x, q1.y); aB1 += bf16x4_to_f32(q1.z, q1.w);
        aA0 += bf16x4_to_f32(q2.x, q2.y); aB0 += bf16x4_to_f32(q2.z, q2.w);
        aA1 += bf16x4_to_f32(q3.x, q3.y); aB1 += bf16x4_to_f32(q3.z, q3.w);
    }
    for (; j < pairs; ++j) {
        unsigned w0 = l32[j];
        unsigned r0 = half ? (w0 >> 16) : (w0 & 0xffffu);
        uint4 q0 = xb4[(size_t)((r0 << 5) + sub)];
        aA0 += bf16x4_to_f32(q0.x, q0.y); aB0 += bf16x4_to_f32(q0.z, q0.w);
    }
    if (n & 1) {
        unsigned w0 = l32[pairs];
        unsigned r0 = w0 & 0xffffu;
        if (half == 0) {
            uint4 q0 = xb4[(size_t)((r0 << 5) + sub)];
            aA0 += bf16x4_to_f32(q0.x, q0.y); aB0 += bf16x4_to_f32(q0.z, q0.w);
        }
    }
    vf4 aA = aA0 + aA1;
    vf4 aB = aB0 + aB1;
#pragma unroll
    for (int k = 0; k < 4; ++k) {
        aA[k] += __shfl_xor(aA[k], 32, 64);
        aB[k] += __shfl_xor(aB[k], 32, 64);
    }
    vf4* o = (vf4*)(out + (size_t)row * DIM2);
    if (half == 0) {
        __builtin_nontemporal_store(aA, &o[2 * sub]);
        __builtin_nontemporal_store(aB, &o[2 * sub + 1]);
    }
    __builtin_nontemporal_store(xown, &o[64 + lane]);
}

extern "C" void kernel_launch(void* const* d_in, const int* in_sizes, int n_in,
                              void* d_out, int out_size, void* d_ws, size_t ws_size,
                              hipStream_t stream) {
    const float* x         = (const float*)d_in[0];
    const int*   batch_idx = (const int*)d_in[1];
    const int*   src_idx   = (const int*)d_in[2];
    const int*   dst_idx   = (const int*)d_in[3];
    float*       out       = (float*)d_out;

    const int E = in_sizes[1];   // 1<<20 edges

    int threads_needed = (E + EPT - 1) / EPT;
    int fillBlocks = (threads_needed + 255) / 256;   // 1024

    // priv layout: cnt8 (2 MB) | bucket_priv (32 MB) | xb (32 MB) = 66 MB
    size_t need_priv = (size_t)RTOT * 8 * 4 + (size_t)RTOT * 256 * 2
                     + (size_t)RTOT * DIM * 2;
    // R8 layout: cnt (256 KB) | bucket (16 MB) | xb (32 MB)
    size_t need_r8 = (size_t)RTOT * 4 + (size_t)RTOT * CAP * 2
                   + (size_t)RTOT * DIM * 2;

    if (ws_size >= need_priv) {
        int* cnt8 = (int*)d_ws;
        unsigned short* bucket = (unsigned short*)(cnt8 + RTOT * 8);
        unsigned short* xb = bucket + (size_t)RTOT * 256;
        zero_counts<<<(RTOT * 8 + 255) / 256, 256, 0, stream>>>(cnt8, RTOT * 8);
        fill_conv_priv<<<fillBlocks + CONV_BLOCKS, 256, 0, stream>>>(
            batch_idx, src_idx, dst_idx, cnt8, bucket, x, xb, E, fillBlocks);
        gather_priv<<<GATHER_BLOCKS, 256, 0, stream>>>(x, xb, cnt8, bucket, out);
    } else {
        // R8 fallback (proven): single bucket, pair-load gather.
        int* cnt = (int*)d_ws;
        unsigned short* bucket = (unsigned short*)(cnt + RTOT);
        unsigned short* xb = bucket + (size_t)RTOT * CAP;
        (void)need_r8;
        zero_counts<<<(RTOT + 255) / 256, 256, 0, stream>>>(cnt, RTOT);
        fill_conv<<<fillBlocks + CONV_BLOCKS, 256, 0, stream>>>(
            batch_idx, src_idx, dst_idx, cnt, bucket, x, xb, E, fillBlocks);
        gather_bf16<<<GATHER_BLOCKS, 256, 0, stream>>>(x, xb, cnt, bucket, out);
    }
}

// Round 10
// 358.437 us; speedup vs baseline: 1.0050x; 1.0050x over previous
//
#include <hip/hip_runtime.h>

// Problem constants (from reference setup_inputs): B=32, N=2048, D=256, E=2^20
#define NB   32
#define NN   2048
#define RTOT (NB * NN)   // 65536 flattened rows
#define DIM  256
#define DIM2 512         // output row stride (concat of accumulator and x)
#define CAP  128         // bucket capacity; P(Poisson(32) > 128) ~ 1e-40

// fill (R1/R7 base, 87us standalone / 94 fused): edges register-held,
// row-window passes cluster each row's ~32 entries (one 64B line) in time.
// REFUTED restructures (do not revisit): R4 row-partition (172us, 8x index
// re-read), R9 XCD-private copies (fill ~106 + gather +50 from 8-segment
// reads). Fill's floor is the atomic-RMW + scattered-writeback path itself.
// R10: NPASS 8->16 (VALU 5.7% -> predicates free; tighter window upside).
#define EPT    4
#define NPASS  16
#define PSHIFT 12        // log2(RTOT / NPASS) = log2(4096)
#define CONV_BLOCKS   512
#define CONV_PER_BLK  (RTOT * DIM / 4 / CONV_BLOCKS)   // 8192 vf4 per block

// gather XCD swizzle (R2, proven): neighbors never cross batches; a batch
// slice fits one XCD's L2. Batch b's blocks all land on XCD b%8.
#define BLKS_PER_BATCH (NN / 4)
#define GATHER_BLOCKS  (RTOT / 4)      // 16384

typedef float vf4 __attribute__((ext_vector_type(4)));
typedef unsigned short vu4 __attribute__((ext_vector_type(4)));

__global__ __launch_bounds__(256) void zero_counts(int* __restrict__ c, int n) {
    int i = blockIdx.x * 256 + threadIdx.x;
    if (i < n) c[i] = 0;
}

// Unpack 4 bf16 (two dwords) into f32x4 via exponent-preserving shifts.
__device__ inline vf4 bf16x4_to_f32(unsigned lo, unsigned hi) {
    vf4 v;
    v[0] = __uint_as_float(lo << 16);
    v[1] = __uint_as_float(lo & 0xffff0000u);
    v[2] = __uint_as_float(hi << 16);
    v[3] = __uint_as_float(hi & 0xffff0000u);
    return v;
}

// Convert path: R10 = fully non-temporal (x read once here; xb is written
// once, read only by gather). Keeps the 96MB stream from evicting fill's
// hot bucket/cnt lines out of L2 mid-pass.
__device__ inline void conv_path(const float* __restrict__ x,
                                 unsigned short* __restrict__ xb, int cb) {
    const vf4* x4 = (const vf4*)x;
    vu4* o4 = (vu4*)xb;
    int beg = cb * CONV_PER_BLK;
    for (int i = beg + (int)threadIdx.x; i < beg + CONV_PER_BLK; i += 256) {
        vf4 v = __builtin_nontemporal_load(&x4[i]);
        vu4 o;
#pragma unroll
        for (int k = 0; k < 4; ++k) {
            unsigned u = __float_as_uint(v[k]);
            unsigned r = u + 0x7fffu + ((u >> 16) & 1u);   // RNE
            o[k] = (unsigned short)(r >> 16);
        }
        __builtin_nontemporal_store(o, &o4[i]);
    }
}

// Fused: blocks [0, fillBlocks) insert buckets; blocks >= fillBlocks convert.
// Fill is latency-bound (VALU ~6%, occ ~53%) so convert runs in its shadow.
__global__ __launch_bounds__(256) void fill_conv(const int* __restrict__ b,
                                                 const int* __restrict__ s,
                                                 const int* __restrict__ d,
                                                 int* __restrict__ cnt,
                                                 unsigned short* __restrict__ bucket,
                                                 const float* __restrict__ x,
                                                 unsigned short* __restrict__ xb,
                                                 int E, int fillBlocks) {
    if ((int)blockIdx.x >= fillBlocks) {
        conv_path(x, xb, blockIdx.x - fillBlocks);
        return;
    }
    int t = blockIdx.x * 256 + threadIdx.x;
    int base = t * EPT;
    int rs[EPT], rd[EPT];
    if (base + EPT <= E) {
        int4 b4 = ((const int4*)b)[t];
        int4 s4 = ((const int4*)s)[t];
        int4 d4 = ((const int4*)d)[t];
        rs[0] = b4.x * NN + s4.x;  rd[0] = b4.x * NN + d4.x;
        rs[1] = b4.y * NN + s4.y;  rd[1] = b4.y * NN + d4.y;
        rs[2] = b4.z * NN + s4.z;  rd[2] = b4.z * NN + d4.z;
        rs[3] = b4.w * NN + s4.w;  rd[3] = b4.w * NN + d4.w;
    } else {
#pragma unroll
        for (int i = 0; i < EPT; ++i) {
            int e = base + i;
            if (e < E) {
                int bb = b[e];
                rs[i] = bb * NN + s[e];
                rd[i] = bb * NN + d[e];
            } else { rs[i] = -1; rd[i] = -1; }   // -1>>PSHIFT==-1: no match
        }
    }
    for (int p = 0; p < NPASS; ++p) {
#pragma unroll
        for (int i = 0; i < EPT; ++i) {
            if ((rs[i] >> PSHIFT) == p) {
                int q = atomicAdd(&cnt[rs[i]], 1);
                if (q < CAP) bucket[(long)rs[i] * CAP + q] = (unsigned short)rd[i];
            }
            if ((rd[i] >> PSHIFT) == p) {
                int q = atomicAdd(&cnt[rd[i]], 1);
                if (q < CAP) bucket[(long)rd[i] * CAP + q] = (unsigned short)rs[i];
            }
        }
    }
}

// gather (R8 pair structure + R10 8-deep MLP): one wave per row; lanes 0-31
// handle the even neighbor of each pair, 32-63 the odd (one uint4 = 8 bf16
// per lane -> one wave-instruction covers TWO 512B neighbor rows). Entry
// words wave-uniform (s_load). Main loop: 8 pair-loads (16 rows) in flight
// to close the gap to the ~55us L2 line-rate floor (R8 4-deep = ~70us).
__global__ __launch_bounds__(256) void gather_bf16(const float* __restrict__ x,
                                                   const unsigned short* __restrict__ xb,
                                                   const int* __restrict__ cnt,
                                                   const unsigned short* __restrict__ bucket,
                                                   float* __restrict__ out) {
    int p = blockIdx.x;
    int l;
    if (gridDim.x == GATHER_BLOCKS) {
        int xcd = p & 7;
        int u   = p >> 3;
        int bat = xcd + 8 * (u >> 9);
        l = bat * BLKS_PER_BATCH + (u & (BLKS_PER_BATCH - 1));
    } else {
        l = p;
    }
    int lane = threadIdx.x & 63;
    int half = lane >> 5;
    int sub  = lane & 31;
    int row = __builtin_amdgcn_readfirstlane((l << 2) + (threadIdx.x >> 6));
    if (row >= RTOT) return;
    int n = __builtin_amdgcn_readfirstlane(cnt[row]);
    if (n > CAP) n = CAP;
    const unsigned* l32 = (const unsigned*)(bucket + (size_t)row * CAP);
    const uint4* xb4 = (const uint4*)xb;
    const vf4*   x4  = (const vf4*)x;
    vf4 xown = x4[((size_t)row << 6) + lane];

    vf4 aA0 = (vf4){0.f,0.f,0.f,0.f};
    vf4 aB0 = (vf4){0.f,0.f,0.f,0.f};
    vf4 aA1 = (vf4){0.f,0.f,0.f,0.f};
    vf4 aB1 = (vf4){0.f,0.f,0.f,0.f};

    int pairs = n >> 1;
    int j = 0;
    // Main: 8 pair-loads in flight = 16 neighbor rows per iteration.
    for (; j + 8 <= pairs; j += 8) {
        unsigned w0 = l32[j + 0], w1 = l32[j + 1];
        unsigned w2 = l32[j + 2], w3 = l32[j + 3];
        unsigned w4 = l32[j + 4], w5 = l32[j + 5];
        unsigned w6 = l32[j + 6], w7 = l32[j + 7];
        unsigned r0 = half ? (w0 >> 16) : (w0 & 0xffffu);
        unsigned r1 = half ? (w1 >> 16) : (w1 & 0xffffu);
        unsigned r2 = half ? (w2 >> 16) : (w2 & 0xffffu);
        unsigned r3 = half ? (w3 >> 16) : (w3 & 0xffffu);
        unsigned r4 = half ? (w4 >> 16) : (w4 & 0xffffu);
        unsigned r5 = half ? (w5 >> 16) : (w5 & 0xffffu);
        unsigned r6 = half ? (w6 >> 16) : (w6 & 0xffffu);
        unsigned r7 = half ? (w7 >> 16) : (w7 & 0xffffu);
        uint4 q0 = xb4[(size_t)((r0 << 5) + sub)];
        uint4 q1 = xb4[(size_t)((r1 << 5) + sub)];
        uint4 q2 = xb4[(size_t)((r2 << 5) + sub)];
        uint4 q3 = xb4[(size_t)((r3 << 5) + sub)];
        uint4 q4 = xb4[(size_t)((r4 << 5) + sub)];
        uint4 q5 = xb4[(size_t)((r5 << 5) + sub)];
        uint4 q6 = xb4[(size_t)((r6 << 5) + sub)];
        uint4 q7 = xb4[(size_t)((r7 << 5) + sub)];
        aA0 += bf16x4_to_f32(q0.x, q0.y); aB0 += bf16x4_to_f32(q0.z, q0.w);
        aA1 += bf16x4_to_f32(q1.x, q1.y); aB1 += bf16x4_to_f32(q1.z, q1.w);
        aA0 += bf16x4_to_f32(q2.x, q2.y); aB0 += bf16x4_to_f32(q2.z, q2.w);
        aA1 += bf16x4_to_f32(q3.x, q3.y); aB1 += bf16x4_to_f32(q3.z, q3.w);
        aA0 += bf16x4_to_f32(q4.x, q4.y); aB0 += bf16x4_to_f32(q4.z, q4.w);
        aA1 += bf16x4_to_f32(q5.x, q5.y); aB1 += bf16x4_to_f32(q5.z, q5.w);
        aA0 += bf16x4_to_f32(q6.x, q6.y); aB0 += bf16x4_to_f32(q6.z, q6.w);
        aA1 += bf16x4_to_f32(q7.x, q7.y); aB1 += bf16x4_to_f32(q7.z, q7.w);
    }
    for (; j + 4 <= pairs; j += 4) {
        unsigned w0 = l32[j + 0], w1 = l32[j + 1];
        unsigned w2 = l32[j + 2], w3 = l32[j + 3];
        unsigned r0 = half ? (w0 >> 16) : (w0 & 0xffffu);
        unsigned r1 = half ? (w1 >> 16) : (w1 & 0xffffu);
        unsigned r2 = half ? (w2 >> 16) : (w2 & 0xffffu);
        unsigned r3 = half ? (w3 >> 16) : (w3 & 0xffffu);
        uint4 q0 = xb4[(size_t)((r0 << 5) + sub)];
        uint4 q1 = xb4[(size_t)((r1 << 5) + sub)];
        uint4 q2 = xb4[(size_t)((r2 << 5) + sub)];
        uint4 q3 = xb4[(size_t)((r3 << 5) + sub)];
        aA0 += bf16x4_to_f32(q0.x, q0.y); aB0 += bf16x4_to_f32(q0.z, q0.w);
        aA1 += bf16x4_to_f32(q1.x, q1.y); aB1 += bf16x4_to_f32(q1.z, q1.w);
        aA0 += bf16x4_to_f32(q2.x, q2.y); aB0 += bf16x4_to_f32(q2.z, q2.w);
        aA1 += bf16x4_to_f32(q3.x, q3.y); aB1 += bf16x4_to_f32(q3.z, q3.w);
    }
    for (; j < pairs; ++j) {
        unsigned w0 = l32[j];
        unsigned r0 = half ? (w0 >> 16) : (w0 & 0xffffu);
        uint4 q0 = xb4[(size_t)((r0 << 5) + sub)];
        aA0 += bf16x4_to_f32(q0.x, q0.y); aB0 += bf16x4_to_f32(q0.z, q0.w);
    }
    if (n & 1) {
        unsigned w0 = l32[pairs];
        unsigned r0 = w0 & 0xffffu;
        if (half == 0) {
            uint4 q0 = xb4[(size_t)((r0 << 5) + sub)];
            aA0 += bf16x4_to_f32(q0.x, q0.y); aB0 += bf16x4_to_f32(q0.z, q0.w);
        }
    }

    vf4 aA = aA0 + aA1;
    vf4 aB = aB0 + aB1;
#pragma unroll
    for (int k = 0; k < 4; ++k) {
        aA[k] += __shfl_xor(aA[k], 32, 64);
        aB[k] += __shfl_xor(aB[k], 32, 64);
    }
    vf4* o = (vf4*)(out + (size_t)row * DIM2);
    if (half == 0) {
        __builtin_nontemporal_store(aA, &o[2 * sub]);
        __builtin_nontemporal_store(aB, &o[2 * sub + 1]);
    }
    __builtin_nontemporal_store(xown, &o[64 + lane]);
}

// Fallback f32 gather (R3 kernel) if workspace can't hold the bf16 copy.
__global__ __launch_bounds__(256) void gather_f32(const float* __restrict__ x,
                                                  const int* __restrict__ cnt,
                                                  const unsigned short* __restrict__ bucket,
                                                  float* __restrict__ out) {
    int p = blockIdx.x;
    int l;
    if (gridDim.x == GATHER_BLOCKS) {
        int xcd = p & 7;
        int u   = p >> 3;
        int bat = xcd + 8 * (u >> 9);
        l = bat * BLKS_PER_BATCH + (u & (BLKS_PER_BATCH - 1));
    } else {
        l = p;
    }
    int lane = threadIdx.x & 63;
    int row = __builtin_amdgcn_readfirstlane((l << 2) + (threadIdx.x >> 6));
    if (row >= RTOT) return;
    int n = __builtin_amdgcn_readfirstlane(cnt[row]);
    if (n > CAP) n = CAP;
    const unsigned* l32 = (const unsigned*)(bucket + (size_t)row * CAP);
    const vf4* x4 = (const vf4*)x;
    vf4 xown = x4[((size_t)row << 6) + lane];
    vf4 acc0 = (vf4){0.f,0.f,0.f,0.f};
    vf4 acc1 = (vf4){0.f,0.f,0.f,0.f};
    vf4 acc2 = (vf4){0.f,0.f,0.f,0.f};
    vf4 acc3 = (vf4){0.f,0.f,0.f,0.f};
    int j = 0;
    for (; j + 8 <= n; j += 8) {
        int k = j >> 1;
        unsigned w0 = l32[k+0], w1 = l32[k+1], w2 = l32[k+2], w3 = l32[k+3];
        unsigned r0 = w0 & 0xffffu, r1 = w0 >> 16;
        unsigned r2 = w1 & 0xffffu, r3 = w1 >> 16;
        unsigned r4 = w2 & 0xffffu, r5 = w2 >> 16;
        unsigned r6 = w3 & 0xffffu, r7 = w3 >> 16;
        vf4 a0 = x4[(size_t)((r0 << 6) + lane)];
        vf4 a1 = x4[(size_t)((r1 << 6) + lane)];
        vf4 a2 = x4[(size_t)((r2 << 6) + lane)];
        vf4 a3 = x4[(size_t)((r3 << 6) + lane)];
        vf4 a4 = x4[(size_t)((r4 << 6) + lane)];
        vf4 a5 = x4[(size_t)((r5 << 6) + lane)];
        vf4 a6 = x4[(size_t)((r6 << 6) + lane)];
        vf4 a7 = x4[(size_t)((r7 << 6) + lane)];
        acc0 += a0; acc1 += a1; acc2 += a2; acc3 += a3;
        acc0 += a4; acc1 += a5; acc2 += a6; acc3 += a7;
    }
    for (; j + 4 <= n; j += 4) {
        int k = j >> 1;
        unsigned w0 = l32[k+0], w1 = l32[k+1];
        unsigned r0 = w0 & 0xffffu, r1 = w0 >> 16;
        unsigned r2 = w1 & 0xffffu, r3 = w1 >> 16;
        vf4 a0 = x4[(size_t)((r0 << 6) + lane)];
        vf4 a1 = x4[(size_t)((r1 << 6) + lane)];
        vf4 a2 = x4[(size_t)((r2 << 6) + lane)];
        vf4 a3 = x4[(size_t)((r3 << 6) + lane)];
        acc0 += a0; acc1 += a1; acc2 += a2; acc3 += a3;
    }
    for (; j < n; ++j) {
        unsigned w0 = l32[j >> 1];
        unsigned r = (j & 1) ? (w0 >> 16) : (w0 & 0xffffu);
        acc0 += x4[(size_t)((r << 6) + lane)];
    }
    vf4 acc = (acc0 + acc1) + (acc2 + acc3);
    vf4* o = (vf4*)(out + (size_t)row * DIM2);
    __builtin_nontemporal_store(acc,  &o[lane]);
    __builtin_nontemporal_store(xown, &o[64 + lane]);
}

extern "C" void kernel_launch(void* const* d_in, const int* in_sizes, int n_in,
                              void* d_out, int out_size, void* d_ws, size_t ws_size,
                              hipStream_t stream) {
    const float* x         = (const float*)d_in[0];
    const int*   batch_idx = (const int*)d_in[1];
    const int*   src_idx   = (const int*)d_in[2];
    const int*   dst_idx   = (const int*)d_in[3];
    float*       out       = (float*)d_out;

    const int E = in_sizes[1];   // 1<<20 edges

    int threads_needed = (E + EPT - 1) / EPT;
    int fillBlocks = (threads_needed + 255) / 256;   // 1024

    // Workspace: cnt (256 KB) | bucket (16 MB) | xb bf16 copy (32 MB)
    int* cnt = (int*)d_ws;
    unsigned short* bucket = (unsigned short*)(cnt + RTOT);
    unsigned short* xb = bucket + (size_t)RTOT * CAP;
    size_t need = (size_t)RTOT * 4 + (size_t)RTOT * CAP * 2 + (size_t)RTOT * DIM * 2;
    bool use_bf16 = (ws_size >= need);

    zero_counts<<<(RTOT + 255) / 256, 256, 0, stream>>>(cnt, RTOT);

    int grid = fillBlocks + (use_bf16 ? CONV_BLOCKS : 0);
    fill_conv<<<grid, 256, 0, stream>>>(batch_idx, src_idx, dst_idx,
                                        cnt, bucket, x, xb, E, fillBlocks);

    if (use_bf16) {
        gather_bf16<<<GATHER_BLOCKS, 256, 0, stream>>>(x, xb, cnt, bucket, out);
    } else {
        gather_f32<<<GATHER_BLOCKS, 256, 0, stream>>>(x, cnt, bucket, out);
    }
}

// Round 11
// 294.870 us; speedup vs baseline: 1.2216x; 1.2156x over previous
//
#include <hip/hip_runtime.h>

// Problem constants (from reference setup_inputs): B=32, N=2048, D=256, E=2^20
#define NB   32
#define NN   2048
#define RTOT (NB * NN)   // 65536 flattened rows
#define DIM  256
#define DIM2 512         // output row stride (concat of accumulator and x)
#define CAP  128         // bucket capacity; P(Poisson(32) > 128) ~ 1e-40

// fill (R1/R7 structure, 87us standalone / 94 fused): edges register-held, 8
// row-window passes cluster each row's ~32 bucket entries (one 64B line) in
// time -> L2 coalesces writebacks.
// REFUTED (do not revisit): R4 row-partition (172us); R9 XCD-private copies
// (fill ~106, gather +36 from 8-segment reads); R10 NPASS=16 (+~25us, VGPR
// 12->28, no WRITE reduction); R10 gather 8-deep unroll (+~36us, TLP loss);
// R5 cooperative fusion (never executes under harness graph capture).
#define EPT    4
#define NPASS  8
#define PSHIFT 13        // log2(RTOT / NPASS)
#define CONV_BLOCKS   512
#define CONV_PER_BLK  (RTOT * DIM / 4 / CONV_BLOCKS)   // 8192 vf4 per block

// gather XCD swizzle (R2, proven): neighbors never cross batches; a batch
// slice fits one XCD's L2. Batch b's blocks all land on XCD b%8.
#define BLKS_PER_BATCH (NN / 4)
#define GATHER_BLOCKS  (RTOT / 4)      // 16384

typedef float vf4 __attribute__((ext_vector_type(4)));
typedef unsigned short vu4 __attribute__((ext_vector_type(4)));

__global__ __launch_bounds__(256) void zero_counts(int* __restrict__ c, int n) {
    int i = blockIdx.x * 256 + threadIdx.x;
    if (i < n) c[i] = 0;
}

// Unpack 4 bf16 (two dwords) into f32x4 via exponent-preserving shifts.
__device__ inline vf4 bf16x4_to_f32(unsigned lo, unsigned hi) {
    vf4 v;
    v[0] = __uint_as_float(lo << 16);
    v[1] = __uint_as_float(lo & 0xffff0000u);
    v[2] = __uint_as_float(hi << 16);
    v[3] = __uint_as_float(hi & 0xffff0000u);
    return v;
}

// Convert path (plain loads/stores -- R10's NT variant was part of a +25us
// regression; reverted).
__device__ inline void conv_path(const float* __restrict__ x,
                                 unsigned short* __restrict__ xb, int cb) {
    const vf4* x4 = (const vf4*)x;
    vu4* o4 = (vu4*)xb;
    int beg = cb * CONV_PER_BLK;
    for (int i = beg + (int)threadIdx.x; i < beg + CONV_PER_BLK; i += 256) {
        vf4 v = x4[i];
        vu4 o;
#pragma unroll
        for (int k = 0; k < 4; ++k) {
            unsigned u = __float_as_uint(v[k]);
            unsigned r = u + 0x7fffu + ((u >> 16) & 1u);   // RNE
            o[k] = (unsigned short)(r >> 16);
        }
        o4[i] = o;
    }
}

// Fused: blocks [0, fillBlocks) insert buckets; blocks >= fillBlocks convert.
// Fill is latency-bound (VALU ~6%, occ ~53%) so convert runs in its shadow
// (+7us vs +20us serialized, measured R8).
__global__ __launch_bounds__(256) void fill_conv(const int* __restrict__ b,
                                                 const int* __restrict__ s,
                                                 const int* __restrict__ d,
                                                 int* __restrict__ cnt,
                                                 unsigned short* __restrict__ bucket,
                                                 const float* __restrict__ x,
                                                 unsigned short* __restrict__ xb,
                                                 int E, int fillBlocks) {
    if ((int)blockIdx.x >= fillBlocks) {
        conv_path(x, xb, blockIdx.x - fillBlocks);
        return;
    }
    int t = blockIdx.x * 256 + threadIdx.x;
    int base = t * EPT;
    int rs[EPT], rd[EPT];
    if (base + EPT <= E) {
        int4 b4 = ((const int4*)b)[t];
        int4 s4 = ((const int4*)s)[t];
        int4 d4 = ((const int4*)d)[t];
        rs[0] = b4.x * NN + s4.x;  rd[0] = b4.x * NN + d4.x;
        rs[1] = b4.y * NN + s4.y;  rd[1] = b4.y * NN + d4.y;
        rs[2] = b4.z * NN + s4.z;  rd[2] = b4.z * NN + d4.z;
        rs[3] = b4.w * NN + s4.w;  rd[3] = b4.w * NN + d4.w;
    } else {
#pragma unroll
        for (int i = 0; i < EPT; ++i) {
            int e = base + i;
            if (e < E) {
                int bb = b[e];
                rs[i] = bb * NN + s[e];
                rd[i] = bb * NN + d[e];
            } else { rs[i] = -1; rd[i] = -1; }   // -1>>PSHIFT==-1: no match
        }
    }
    for (int p = 0; p < NPASS; ++p) {
#pragma unroll
        for (int i = 0; i < EPT; ++i) {
            if ((rs[i] >> PSHIFT) == p) {
                int q = atomicAdd(&cnt[rs[i]], 1);
                if (q < CAP) bucket[(long)rs[i] * CAP + q] = (unsigned short)rd[i];
            }
            if ((rd[i] >> PSHIFT) == p) {
                int q = atomicAdd(&cnt[rd[i]], 1);
                if (q < CAP) bucket[(long)rd[i] * CAP + q] = (unsigned short)rs[i];
            }
        }
    }
}

// gather (R8, proven ~70us): one wave per row; lanes 0-31 handle the even
// neighbor of each pair, 32-63 the odd (one uint4 = 8 bf16 per lane -> one
// wave-instruction covers TWO 512B neighbor rows). Entry words wave-uniform
// (s_load). 4 pair-loads in flight (8-deep regressed: TLP loss, R10).
__global__ __launch_bounds__(256) void gather_bf16(const float* __restrict__ x,
                                                   const unsigned short* __restrict__ xb,
                                                   const int* __restrict__ cnt,
                                                   const unsigned short* __restrict__ bucket,
                                                   float* __restrict__ out) {
    int p = blockIdx.x;
    int l;
    if (gridDim.x == GATHER_BLOCKS) {
        int xcd = p & 7;
        int u   = p >> 3;
        int bat = xcd + 8 * (u >> 9);
        l = bat * BLKS_PER_BATCH + (u & (BLKS_PER_BATCH - 1));
    } else {
        l = p;
    }
    int lane = threadIdx.x & 63;
    int half = lane >> 5;
    int sub  = lane & 31;
    int row = __builtin_amdgcn_readfirstlane((l << 2) + (threadIdx.x >> 6));
    if (row >= RTOT) return;
    int n = __builtin_amdgcn_readfirstlane(cnt[row]);
    if (n > CAP) n = CAP;
    const unsigned* l32 = (const unsigned*)(bucket + (size_t)row * CAP);
    const uint4* xb4 = (const uint4*)xb;
    const vf4*   x4  = (const vf4*)x;
    vf4 xown = x4[((size_t)row << 6) + lane];
    vf4 aA0 = (vf4){0.f,0.f,0.f,0.f};
    vf4 aB0 = (vf4){0.f,0.f,0.f,0.f};
    vf4 aA1 = (vf4){0.f,0.f,0.f,0.f};
    vf4 aB1 = (vf4){0.f,0.f,0.f,0.f};
    int pairs = n >> 1;
    int j = 0;
    for (; j + 4 <= pairs; j += 4) {
        unsigned w0 = l32[j + 0], w1 = l32[j + 1], w2 = l32[j + 2], w3 = l32[j + 3];
        unsigned r0 = half ? (w0 >> 16) : (w0 & 0xffffu);
        unsigned r1 = half ? (w1 >> 16) : (w1 & 0xffffu);
        unsigned r2 = half ? (w2 >> 16) : (w2 & 0xffffu);
        unsigned r3 = half ? (w3 >> 16) : (w3 & 0xffffu);
        uint4 q0 = xb4[(size_t)((r0 << 5) + sub)];
        uint4 q1 = xb4[(size_t)((r1 << 5) + sub)];
        uint4 q2 = xb4[(size_t)((r2 << 5) + sub)];
        uint4 q3 = xb4[(size_t)((r3 << 5) + sub)];
        aA0 += bf16x4_to_f32(q0.x, q0.y); aB0 += bf16x4_to_f32(q0.z, q0.w);
        aA1 += bf16x4_to_f32(q1.x, q1.y); aB1 += bf16x4_to_f32(q1.z, q1.w);
        aA0 += bf16x4_to_f32(q2.x, q2.y); aB0 += bf16x4_to_f32(q2.z, q2.w);
        aA1 += bf16x4_to_f32(q3.x, q3.y); aB1 += bf16x4_to_f32(q3.z, q3.w);
    }
    for (; j < pairs; ++j) {
        unsigned w0 = l32[j];
        unsigned r0 = half ? (w0 >> 16) : (w0 & 0xffffu);
        uint4 q0 = xb4[(size_t)((r0 << 5) + sub)];
        aA0 += bf16x4_to_f32(q0.x, q0.y); aB0 += bf16x4_to_f32(q0.z, q0.w);
    }
    if (n & 1) {
        unsigned w0 = l32[pairs];
        unsigned r0 = w0 & 0xffffu;
        if (half == 0) {
            uint4 q0 = xb4[(size_t)((r0 << 5) + sub)];
            aA0 += bf16x4_to_f32(q0.x, q0.y); aB0 += bf16x4_to_f32(q0.z, q0.w);
        }
    }
    vf4 aA = aA0 + aA1;
    vf4 aB = aB0 + aB1;
#pragma unroll
    for (int k = 0; k < 4; ++k) {
        aA[k] += __shfl_xor(aA[k], 32, 64);
        aB[k] += __shfl_xor(aB[k], 32, 64);
    }
    vf4* o = (vf4*)(out + (size_t)row * DIM2);
    if (half == 0) {
        __builtin_nontemporal_store(aA, &o[2 * sub]);
        __builtin_nontemporal_store(aB, &o[2 * sub + 1]);
    }
    __builtin_nontemporal_store(xown, &o[64 + lane]);
}

// Fallback f32 gather (R3 kernel) if workspace can't hold the bf16 copy.
__global__ __launch_bounds__(256) void gather_f32(const float* __restrict__ x,
                                                  const int* __restrict__ cnt,
                                                  const unsigned short* __restrict__ bucket,
                                                  float* __restrict__ out) {
    int p = blockIdx.x;
    int l;
    if (gridDim.x == GATHER_BLOCKS) {
        int xcd = p & 7;
        int u   = p >> 3;
        int bat = xcd + 8 * (u >> 9);
        l = bat * BLKS_PER_BATCH + (u & (BLKS_PER_BATCH - 1));
    } else {
        l = p;
    }
    int lane = threadIdx.x & 63;
    int row = __builtin_amdgcn_readfirstlane((l << 2) + (threadIdx.x >> 6));
    if (row >= RTOT) return;
    int n = __builtin_amdgcn_readfirstlane(cnt[row]);
    if (n > CAP) n = CAP;
    const unsigned* l32 = (const unsigned*)(bucket + (size_t)row * CAP);
    const vf4* x4 = (const vf4*)x;
    vf4 xown = x4[((size_t)row << 6) + lane];
    vf4 acc0 = (vf4){0.f,0.f,0.f,0.f};
    vf4 acc1 = (vf4){0.f,0.f,0.f,0.f};
    vf4 acc2 = (vf4){0.f,0.f,0.f,0.f};
    vf4 acc3 = (vf4){0.f,0.f,0.f,0.f};
    int j = 0;
    for (; j + 8 <= n; j += 8) {
        int k = j >> 1;
        unsigned w0 = l32[k+0], w1 = l32[k+1], w2 = l32[k+2], w3 = l32[k+3];
        unsigned r0 = w0 & 0xffffu, r1 = w0 >> 16;
        unsigned r2 = w1 & 0xffffu, r3 = w1 >> 16;
        unsigned r4 = w2 & 0xffffu, r5 = w2 >> 16;
        unsigned r6 = w3 & 0xffffu, r7 = w3 >> 16;
        vf4 a0 = x4[(size_t)((r0 << 6) + lane)];
        vf4 a1 = x4[(size_t)((r1 << 6) + lane)];
        vf4 a2 = x4[(size_t)((r2 << 6) + lane)];
        vf4 a3 = x4[(size_t)((r3 << 6) + lane)];
        vf4 a4 = x4[(size_t)((r4 << 6) + lane)];
        vf4 a5 = x4[(size_t)((r5 << 6) + lane)];
        vf4 a6 = x4[(size_t)((r6 << 6) + lane)];
        vf4 a7 = x4[(size_t)((r7 << 6) + lane)];
        acc0 += a0; acc1 += a1; acc2 += a2; acc3 += a3;
        acc0 += a4; acc1 += a5; acc2 += a6; acc3 += a7;
    }
    for (; j + 4 <= n; j += 4) {
        int k = j >> 1;
        unsigned w0 = l32[k+0], w1 = l32[k+1];
        unsigned r0 = w0 & 0xffffu, r1 = w0 >> 16;
        unsigned r2 = w1 & 0xffffu, r3 = w1 >> 16;
        vf4 a0 = x4[(size_t)((r0 << 6) + lane)];
        vf4 a1 = x4[(size_t)((r1 << 6) + lane)];
        vf4 a2 = x4[(size_t)((r2 << 6) + lane)];
        vf4 a3 = x4[(size_t)((r3 << 6) + lane)];
        acc0 += a0; acc1 += a1; acc2 += a2; acc3 += a3;
    }
    for (; j < n; ++j) {
        unsigned w0 = l32[j >> 1];
        unsigned r = (j & 1) ? (w0 >> 16) : (w0 & 0xffffu);
        acc0 += x4[(size_t)((r << 6) + lane)];
    }
    vf4 acc = (acc0 + acc1) + (acc2 + acc3);
    vf4* o = (vf4*)(out + (size_t)row * DIM2);
    __builtin_nontemporal_store(acc,  &o[lane]);
    __builtin_nontemporal_store(xown, &o[64 + lane]);
}

extern "C" void kernel_launch(void* const* d_in, const int* in_sizes, int n_in,
                              void* d_out, int out_size, void* d_ws, size_t ws_size,
                              hipStream_t stream) {
    const float* x         = (const float*)d_in[0];
    const int*   batch_idx = (const int*)d_in[1];
    const int*   src_idx   = (const int*)d_in[2];
    const int*   dst_idx   = (const int*)d_in[3];
    float*       out       = (float*)d_out;

    const int E = in_sizes[1];   // 1<<20 edges

    int threads_needed = (E + EPT - 1) / EPT;
    int fillBlocks = (threads_needed + 255) / 256;   // 1024

    // Workspace: cnt (256 KB) | bucket (16 MB) | xb bf16 copy (32 MB)
    int* cnt = (int*)d_ws;
    unsigned short* bucket = (unsigned short*)(cnt + RTOT);
    unsigned short* xb = bucket + (size_t)RTOT * CAP;
    size_t need = (size_t)RTOT * 4 + (size_t)RTOT * CAP * 2 + (size_t)RTOT * DIM * 2;
    bool use_bf16 = (ws_size >= need);

    zero_counts<<<(RTOT + 255) / 256, 256, 0, stream>>>(cnt, RTOT);

    int grid = fillBlocks + (use_bf16 ? CONV_BLOCKS : 0);
    fill_conv<<<grid, 256, 0, stream>>>(batch_idx, src_idx, dst_idx,
                                        cnt, bucket, x, xb, E, fillBlocks);

    if (use_bf16) {
        gather_bf16<<<GATHER_BLOCKS, 256, 0, stream>>>(x, xb, cnt, bucket, out);
    } else {
        gather_f32<<<GATHER_BLOCKS, 256, 0, stream>>>(x, cnt, bucket, out);
    }
}